// Round 5
// baseline (947.380 us; speedup 1.0000x reference)
//
#include <hip/hip_runtime.h>

#define B_ 4096
#define T_ 128
#define DD_ 21
#define H_ 64
#define L_ 32
#define DP_ 32   // layer-0 input dim padded to 32 (f16)

typedef _Float16 f16;
typedef _Float16 f16x8 __attribute__((ext_vector_type(8)));
typedef _Float16 f16x4 __attribute__((ext_vector_type(4)));
typedef float f32x4 __attribute__((ext_vector_type(4)));

#if __has_builtin(__builtin_amdgcn_exp2f)
#define EXP2F(x) __builtin_amdgcn_exp2f(x)
#else
#define EXP2F(x) exp2f(x)
#endif
#if __has_builtin(__builtin_amdgcn_rcpf)
#define RCPF(x) __builtin_amdgcn_rcpf(x)
#else
#define RCPF(x) (1.0f / (x))
#endif

__device__ __forceinline__ float sigmoid_(float x) {
    return RCPF(1.0f + EXP2F(-1.4426950408889634f * x));
}
__device__ __forceinline__ float tanh_(float x) {
    return 1.0f - 2.0f * RCPF(1.0f + EXP2F(2.8853900817779268f * x));
}

#define MFMA16(A, Bf, C) __builtin_amdgcn_mfma_f32_16x16x32_f16((A), (Bf), (C), 0, 0, 0)

// ---- h rings: [2 slots][16 rows][64 cols] f16, XOR-swizzled rows ----
// write: D-frag (row=lh*4+r, col); read: A-frag, role selects k-half (cols 0-31 / 32-63)
__device__ __forceinline__ f16x8 ring_read_frag(const f16* ring, int slot, int l15, int lh, int role) {
    const char* base = (const char*)(ring + slot * 1024);
    const int sw = (l15 & 7) << 4;
    return *(const f16x8*)(base + l15 * 128 + (((role << 6) + lh * 16) ^ sw));
}
__device__ __forceinline__ void ring_read_full(const f16* ring, int slot, int l15, int lh,
                                               f16x8& a0, f16x8& a1) {
    const char* base = (const char*)(ring + slot * 1024);
    const int sw = (l15 & 7) << 4;
    a0 = *(const f16x8*)(base + l15 * 128 + ((lh * 16) ^ sw));
    a1 = *(const f16x8*)(base + l15 * 128 + ((64 + lh * 16) ^ sw));
}

// x pad/cast: x f32 [B,T,21] -> xpad f16 [B,T,32] (zero-padded)
__global__ __launch_bounds__(256)
void padx_k(const float* __restrict__ x, f16* __restrict__ xpad)
{
    const int idx = blockIdx.x * blockDim.x + threadIdx.x;   // B*T*8 groups of 4
    const size_t bt = (size_t)(idx >> 3);
    const int k0 = (idx & 7) * 4;
    const float* src = x + bt * DD_;
    f16x4 v;
#pragma unroll
    for (int j = 0; j < 4; ++j) {
        const int k = k0 + j;
        v[j] = (k < DD_) ? (f16)src[k] : (f16)0.0f;
    }
    *(f16x4*)(xpad + bt * DP_ + k0) = v;
}

// Fused layer pair, 1-step skew, K-SPLIT wave pairs.
// Block: 1024 thr = 16 waves = 4 waves/SIMD. wv: layer=wv>>3, hct=(wv>>1)&3, role=wv&1.
// Role A (0): k=0..31 weight frags; role B (1): k=32..63. Partial gate accs are
// summed via a b128 LDS exchange; activations split by rows (A: r0,1; B: r2,3).
// Per-wave regs ~110 -> 4 waves/EU under __launch_bounds__(1024,4) budget (128).
// Two barriers/step: B1 = exchange visibility, B2 = ring visibility.
template<bool IS_DEC>
__global__ __launch_bounds__(1024, 4)
void lstm_pair_k(const f16* __restrict__ xpad,
                 const float* __restrict__ Wih0, const float* __restrict__ Whh0,
                 const float* __restrict__ bih0, const float* __restrict__ bhh0,
                 const float* __restrict__ Wih1, const float* __restrict__ Whh1,
                 const float* __restrict__ bih1, const float* __restrict__ bhh1,
                 const float* __restrict__ h0p,
                 float* __restrict__ hT_out,
                 const float* __restrict__ outW, const float* __restrict__ outb,
                 float* __restrict__ rec_out)
{
    __shared__ __align__(16) f16 ring0[2 * 1024];          // h1 ring (4 KB)
    __shared__ __align__(16) f16 ring1[2 * 1024];          // h2 ring (4 KB)
    __shared__ __align__(16) f32x4 exch[8][2][2][64];      // [pair][destRole][qhalf][lane] 32 KB

    const int tid  = threadIdx.x;
    const int wv   = tid >> 6;
    const int layer = wv >> 3;        // 0 / 1
    const int hct  = (wv >> 1) & 3;   // hidden-col tile
    const int role = wv & 1;          // 0: k-low, 1: k-high
    const int pidx = wv >> 1;         // exchange pair index (0..7)
    const int lane = tid & 63;
    const int l15  = lane & 15;
    const int lh   = lane >> 4;
    const int rk   = role * 2;        // my act rows (r = rk, rk+1)
    const int rbase = blockIdx.x * 16;

    const float* Wih = layer ? Wih1 : Wih0;
    const float* Whh = layer ? Whh1 : Whh0;
    const float* bih = layer ? bih1 : bih0;
    const float* bhh = layer ? bhh1 : bhh0;

    // ---- weight frags -> VGPRs (B-frag: col=l15, k = lh*8+j within my k-half) ----
    f16x8 wh[4];     // Whh, my k-half, q=0..3
    f16x8 xw[4];     // layer1: Wih my k-half q=0..3; layer0: q = role*2 + {0,1} in xw[0..1]
    float biasv[4];
#pragma unroll
    for (int q = 0; q < 4; ++q) {
        const int g = (hct + 4 * q) * 16 + l15;   // gate col; q=0:i 1:f 2:g 3:o
        {
            const float* p = Whh + g * H_ + role * 32 + lh * 8;
            f16x8 v;
#pragma unroll
            for (int j = 0; j < 8; ++j) v[j] = (f16)p[j];
            wh[q] = v;
        }
        if (layer) {
            const float* p = Wih + g * H_ + role * 32 + lh * 8;
            f16x8 v;
#pragma unroll
            for (int j = 0; j < 8; ++j) v[j] = (f16)p[j];
            xw[q] = v;
        }
        biasv[q] = bih[g] + bhh[g];
    }
    if (!layer) {
        // layer0 x-weights: full K=32 frags for my two q's (q = rk, rk+1)
#pragma unroll
        for (int qq = 0; qq < 2; ++qq) {
            const int g = (hct + 4 * (rk + qq)) * 16 + l15;
            const float* p = Wih + g * DD_;
            f16x8 v;
#pragma unroll
            for (int j = 0; j < 8; ++j) {
                const int k = lh * 8 + j;
                v[j] = (k < DD_) ? (f16)p[k] : (f16)0.0f;
            }
            xw[qq] = v;
        }
        xw[2] = xw[0]; xw[3] = xw[1];  // keep defined
    }

    // out-projection (dec): waves wv==5 (d 0-15), wv==7 (d 16-20), full-K
    f16x8 bO[2];
    float obias = 0.0f;
    const bool projw = IS_DEC && (!layer) && role == 1 && hct >= 2;
    if (IS_DEC) {
        const int dt = hct - 2;
        const bool pvalid = projw && (dt * 16 + l15 < DD_);
        const int d = pvalid ? (dt * 16 + l15) : 0;
#pragma unroll
        for (int kt = 0; kt < 2; ++kt) {
            f16x8 v;
#pragma unroll
            for (int j = 0; j < 8; ++j)
                v[j] = pvalid ? (f16)outW[d * H_ + kt * 32 + lh * 8 + j] : (f16)0.0f;
            bO[kt] = v;
        }
        if (pvalid) obias = outb[d];
    }

    // ---- init ring slot 1 with h(-1): h0p (dec) or zeros (enc) ----
    if (tid < 512) {
        f16* ring = (tid < 256) ? ring0 : ring1;
        const int i = tid & 255;
        const int row = i >> 4;
        const int cq = i & 15;
        f16x4 v;
#pragma unroll
        for (int j = 0; j < 4; ++j)
            v[j] = IS_DEC ? (f16)h0p[(size_t)(rbase + row) * H_ + cq * 4 + j] : (f16)0.0f;
        char* base = (char*)(ring + 1024);
        *(f16x4*)(base + row * 128 + ((cq * 8) ^ ((row & 7) << 4))) = v;
    }

    float c2[2] = {0.f, 0.f};

    // ---- layer0 x prefetch (distance 2, both roles load same addr -> L1 hit) ----
    auto xaddr = [&](int t) -> const f16* {
        const int trd = IS_DEC ? (T_ - 1 - t) : t;
        return xpad + ((size_t)(rbase + l15) * T_ + trd) * DP_ + lh * 8;
    };
    f16x8 xA, pf[2];
    if (!layer) {
        xA = *(const f16x8*)xaddr(0);
        pf[1] = *(const f16x8*)xaddr(1);
    }

    __syncthreads();   // ring init visible

    const f32x4 zero4 = {0.f, 0.f, 0.f, 0.f};

#pragma unroll 2
    for (int s = 0; s < 130; ++s) {
        const bool act0 = (!layer) ? (s < T_) : (s >= 1 && s <= T_);
        f32x4 acc[4];

        // ================= phase 1: partial MFMAs + exchange write =================
        if (!layer) {
            if (act0) {
                const int tf = (s + 2 < T_) ? s + 2 : T_ - 1;
                pf[s & 1] = *(const f16x8*)xaddr(tf);
                const f16x8 hA = ring_read_frag(ring0, (s + 1) & 1, l15, lh, role);
#pragma unroll
                for (int q = 0; q < 4; ++q) acc[q] = MFMA16(hA, wh[q], zero4);
                acc[rk + 0] = MFMA16(xA, xw[0], acc[rk + 0]);
                acc[rk + 1] = MFMA16(xA, xw[1], acc[rk + 1]);
            }
            // deferred output projection of h2(s-2), full-K, no exchange
            if (projw && s >= 2) {
                f16x8 pA0, pA1;
                ring_read_full(ring1, s & 1, l15, lh, pA0, pA1);
                f32x4 ao = {obias, obias, obias, obias};
                ao = MFMA16(pA0, bO[0], ao);
                ao = MFMA16(pA1, bO[1], ao);
                const int d = (hct - 2) * 16 + l15;
                if (d < DD_) {
                    const int t = s - 2;
#pragma unroll
                    for (int r = 0; r < 4; ++r)
                        rec_out[((size_t)(rbase + lh * 4 + r) * T_ + (T_ - 1 - t)) * DD_ + d] = ao[r];
                }
            }
        } else {
            if (act0) {
                const f16x8 h1A = ring_read_frag(ring0, (s + 1) & 1, l15, lh, role);
                const f16x8 h2A = ring_read_frag(ring1, s & 1, l15, lh, role);
#pragma unroll
                for (int q = 0; q < 4; ++q) {
                    f32x4 a = MFMA16(h1A, xw[q], zero4);
                    acc[q] = MFMA16(h2A, wh[q], a);
                }
            }
        }
        if (act0) {
            // send partner's rows: rs = (role^1)*2
            const int rs = (role ^ 1) * 2;
            f32x4 s0 = {acc[0][rs], acc[0][rs + 1], acc[1][rs], acc[1][rs + 1]};
            f32x4 s1 = {acc[2][rs], acc[2][rs + 1], acc[3][rs], acc[3][rs + 1]};
            exch[pidx][role ^ 1][0][lane] = s0;
            exch[pidx][role ^ 1][1][lane] = s1;
        }
        __syncthreads();   // B1: exchange visible

        // ================= phase 2: sum partials, activations, ring write =========
        if (act0) {
            const f32x4 g0 = exch[pidx][role][0][lane];
            const f32x4 g1 = exch[pidx][role][1][lane];
            f16 hh[2];
            float hvf[2];
#pragma unroll
            for (int rloc = 0; rloc < 2; ++rloc) {
                const float si = acc[0][rk + rloc] + (rloc ? g0[1] : g0[0]) + biasv[0];
                const float sf = acc[1][rk + rloc] + (rloc ? g0[3] : g0[2]) + biasv[1];
                const float sg = acc[2][rk + rloc] + (rloc ? g1[1] : g1[0]) + biasv[2];
                const float so = acc[3][rk + rloc] + (rloc ? g1[3] : g1[2]) + biasv[3];
                const float iv = sigmoid_(si);
                const float fv = sigmoid_(sf);
                const float gv = tanh_(sg);
                const float ov = sigmoid_(so);
                const float cn = fv * c2[rloc] + iv * gv;
                c2[rloc] = cn;
                hvf[rloc] = ov * tanh_(cn);
                hh[rloc] = (f16)hvf[rloc];
            }
            // ring write: 2 rows (row = lh*4 + rk + rloc)
            f16* ring = layer ? ring1 : ring0;
            const int slot = layer ? ((s + 1) & 1) : (s & 1);
            char* base = (char*)(ring + slot * 1024);
            const int colb = (hct * 16 + l15) * 2;
#pragma unroll
            for (int rloc = 0; rloc < 2; ++rloc) {
                const int row = lh * 4 + rk + rloc;
                *(f16*)(base + row * 128 + (colb ^ ((row & 7) << 4))) = hh[rloc];
            }
            if (!IS_DEC && layer && s == T_) {
#pragma unroll
                for (int rloc = 0; rloc < 2; ++rloc)
                    hT_out[(size_t)(rbase + lh * 4 + rk + rloc) * H_ + hct * 16 + l15] = hvf[rloc];
            }
            if (!layer) xA = pf[(s + 1) & 1];
        }
        __syncthreads();   // B2: ring visible
    }
}

// latent = hT2 @ tlW^T + tlb ; h0 = latent @ flW^T + flb   (tiny, fp32 VALU)
__global__ __launch_bounds__(256)
void latent_k(const float* __restrict__ hT, const float* __restrict__ tlW,
              const float* __restrict__ tlb, const float* __restrict__ flW,
              const float* __restrict__ flb, float* __restrict__ lat_out,
              float* __restrict__ h0_out)
{
    __shared__ float lat[64][L_];
    const int tid = threadIdx.x;
    const int r = tid >> 2;
    const int rb = blockIdx.x * 64;

    float hr[H_];
    const float* hrow = hT + (size_t)(rb + r) * H_;
#pragma unroll
    for (int k = 0; k < H_; ++k) hr[k] = hrow[k];

    const int c8 = (tid & 3) * 8;
#pragma unroll
    for (int jj = 0; jj < 8; ++jj) {
        const int l = c8 + jj;
        float s = tlb[l];
        const float* wrow = tlW + l * H_;
#pragma unroll
        for (int k = 0; k < H_; ++k) s += hr[k] * wrow[k];
        lat[r][l] = s;
        lat_out[(size_t)(rb + r) * L_ + l] = s;
    }
    __syncthreads();

    float lr[L_];
#pragma unroll
    for (int k = 0; k < L_; ++k) lr[k] = lat[r][k];
    const int hc16 = (tid & 3) * 16;
#pragma unroll
    for (int jj = 0; jj < 16; ++jj) {
        const int hc = hc16 + jj;
        float s = flb[hc];
        const float* wrow = flW + hc * L_;
#pragma unroll
        for (int k = 0; k < L_; ++k) s += lr[k] * wrow[k];
        h0_out[(size_t)(rb + r) * H_ + hc] = s;
    }
}

extern "C" void kernel_launch(void* const* d_in, const int* in_sizes, int n_in,
                              void* d_out, int out_size, void* d_ws, size_t ws_size,
                              hipStream_t stream)
{
    const float* x     = (const float*)d_in[0];
    const float* eWih0 = (const float*)d_in[1];
    const float* eWhh0 = (const float*)d_in[2];
    const float* ebih0 = (const float*)d_in[3];
    const float* ebhh0 = (const float*)d_in[4];
    const float* eWih1 = (const float*)d_in[5];
    const float* eWhh1 = (const float*)d_in[6];
    const float* ebih1 = (const float*)d_in[7];
    const float* ebhh1 = (const float*)d_in[8];
    const float* dWih0 = (const float*)d_in[9];
    const float* dWhh0 = (const float*)d_in[10];
    const float* dbih0 = (const float*)d_in[11];
    const float* dbhh0 = (const float*)d_in[12];
    const float* dWih1 = (const float*)d_in[13];
    const float* dWhh1 = (const float*)d_in[14];
    const float* dbih1 = (const float*)d_in[15];
    const float* dbhh1 = (const float*)d_in[16];
    const float* tlW   = (const float*)d_in[17];
    const float* tlb   = (const float*)d_in[18];
    const float* flW   = (const float*)d_in[19];
    const float* flb   = (const float*)d_in[20];
    const float* outW  = (const float*)d_in[21];
    const float* outb  = (const float*)d_in[22];

    float* rec = (float*)d_out;                       // [B,T,21] fp32
    float* lat = rec + (size_t)B_ * T_ * DD_;         // [B,32]  fp32

    char* ws = (char*)d_ws;
    f16*   xpad = (f16*)ws;                                            // [B,T,32] f16
    float* hT2  = (float*)(ws + (size_t)B_ * T_ * DP_ * 2);            // [B,64]
    float* h0   = (float*)(ws + (size_t)B_ * T_ * DP_ * 2 + (size_t)B_ * H_ * 4); // [B,64]

    // pad/cast x once per call
    padx_k<<<dim3(B_ * T_ * 8 / 256), dim3(256), 0, stream>>>(x, xpad);
    // fused encoder pair -> hT2
    lstm_pair_k<false><<<dim3(B_ / 16), dim3(1024), 0, stream>>>(
        xpad, eWih0, eWhh0, ebih0, ebhh0, eWih1, eWhh1, ebih1, ebhh1,
        nullptr, hT2, nullptr, nullptr, nullptr);
    // latent + decoder initial h
    latent_k<<<dim3(B_ / 64), dim3(256), 0, stream>>>(hT2, tlW, tlb, flW, flb, lat, h0);
    // fused decoder pair -> rec (fused out-proj, time-reversed store)
    lstm_pair_k<true><<<dim3(B_ / 16), dim3(1024), 0, stream>>>(
        xpad, dWih0, dWhh0, dbih0, dbhh0, dWih1, dWhh1, dbih1, dbhh1,
        h0, nullptr, outW, outb, rec);
}

// Round 7
// 594.136 us; speedup vs baseline: 1.5945x; 1.5945x over previous
//
#include <hip/hip_runtime.h>

#define B_ 4096
#define T_ 128
#define DD_ 21
#define H_ 64
#define L_ 32
#define DP_ 32   // layer-0 input dim padded to 32 (f16)

typedef _Float16 f16;
typedef _Float16 f16x8 __attribute__((ext_vector_type(8)));
typedef _Float16 f16x4 __attribute__((ext_vector_type(4)));
typedef float f32x4 __attribute__((ext_vector_type(4)));
typedef float f32x2 __attribute__((ext_vector_type(2)));

#if __has_builtin(__builtin_amdgcn_exp2f)
#define EXP2F(x) __builtin_amdgcn_exp2f(x)
#else
#define EXP2F(x) exp2f(x)
#endif
#if __has_builtin(__builtin_amdgcn_rcpf)
#define RCPF(x) __builtin_amdgcn_rcpf(x)
#else
#define RCPF(x) (1.0f / (x))
#endif

__device__ __forceinline__ float sigmoid_(float x) {
    return RCPF(1.0f + EXP2F(-1.4426950408889634f * x));
}
__device__ __forceinline__ float tanh_(float x) {
    return 1.0f - 2.0f * RCPF(1.0f + EXP2F(2.8853900817779268f * x));
}

#define MFMA16(A, Bf, C) __builtin_amdgcn_mfma_f32_16x16x32_f16((A), (Bf), (C), 0, 0, 0)

// ---- h rings: [2 slots][16 rows][64 cols] f16, XOR-swizzled rows ----
__device__ __forceinline__ f16x8 ring_read_frag(const f16* ring, int slot, int l15, int lh, int role) {
    const char* base = (const char*)(ring + slot * 1024);
    const int sw = (l15 & 7) << 4;
    return *(const f16x8*)(base + l15 * 128 + (((role << 6) + lh * 16) ^ sw));
}
__device__ __forceinline__ void ring_read_full(const f16* ring, int slot, int l15, int lh,
                                               f16x8& a0, f16x8& a1) {
    const char* base = (const char*)(ring + slot * 1024);
    const int sw = (l15 & 7) << 4;
    a0 = *(const f16x8*)(base + l15 * 128 + ((lh * 16) ^ sw));
    a1 = *(const f16x8*)(base + l15 * 128 + ((64 + lh * 16) ^ sw));
}

// x pad/cast: x f32 [B,T,21] -> xpad f16 [B,T,32] (zero-padded)
__global__ __launch_bounds__(256)
void padx_k(const float* __restrict__ x, f16* __restrict__ xpad)
{
    const int idx = blockIdx.x * blockDim.x + threadIdx.x;   // B*T*8 groups of 4
    const size_t bt = (size_t)(idx >> 3);
    const int k0 = (idx & 7) * 4;
    const float* src = x + bt * DD_;
    f16x4 v;
#pragma unroll
    for (int j = 0; j < 4; ++j) {
        const int k = k0 + j;
        v[j] = (k < DD_) ? (f16)src[k] : (f16)0.0f;
    }
    *(f16x4*)(xpad + bt * DP_ + k0) = v;
}

// Fused layer pair, 1-step skew, K-SPLIT wave pairs.
// Block: 1024 thr = 16 waves = 4 waves/SIMD. wv: layer=wv>>3, hct=(wv>>1)&3, role=wv&1.
// Role 0: k=0..31 frags + act rows {0,1}; role 1: k=32..63 + act rows {2,3}.
// CORRECTNESS-CRITICAL (round-6 failure): MFMA IGNORES EXEC on CDNA. Any MFMA
// under an exec-masked (threadIdx-derived) branch without a guaranteed execz
// skip executes on the wrong waves and corrupts acc. Fixes here:
//  (a) all wave-role conditions derived from readfirstlane (SGPR) -> scalar
//      s_cbranch branches that truly skip their bodies;
//  (b) layer-0 x-MFMA made branchless: all 4 q's, with the 2 q's owned by the
//      partner role loaded as ZERO weight frags (acc[q] += xA*0 is a no-op).
template<bool IS_DEC>
__global__
__attribute__((amdgpu_flat_work_group_size(1024, 1024), amdgpu_waves_per_eu(4, 4)))
void lstm_pair_k(const f16* __restrict__ xpad,
                 const float* __restrict__ Wih0, const float* __restrict__ Whh0,
                 const float* __restrict__ bih0, const float* __restrict__ bhh0,
                 const float* __restrict__ Wih1, const float* __restrict__ Whh1,
                 const float* __restrict__ bih1, const float* __restrict__ bhh1,
                 const float* __restrict__ h0p,
                 float* __restrict__ hT_out,
                 const float* __restrict__ outW, const float* __restrict__ outb,
                 float* __restrict__ rec_out)
{
    __shared__ __align__(16) f16 ring0[2 * 1024];          // h1 ring (4 KB)
    __shared__ __align__(16) f16 ring1[2 * 1024];          // h2 ring (4 KB)
    __shared__ __align__(8) f32x2 exch[8][2][4][64];       // [pair][destRole][q][lane] 32 KB

    const int tid  = threadIdx.x;
    // scalar (SGPR) wave-role identifiers -> scalar branches everywhere below
    const int wvS   = __builtin_amdgcn_readfirstlane(tid >> 6);
    const int layerS = wvS >> 3;        // 0 / 1
    const int hctS  = (wvS >> 1) & 3;   // hidden-col tile
    const int roleS = wvS & 1;          // 0: k-low rows01, 1: k-high rows23
    const int pidxS = wvS >> 1;         // exchange pair index (0..7)
    const int rkS   = roleS * 2;        // my act rows (r = rkS, rkS+1)
    const int lane = tid & 63;
    const int l15  = lane & 15;
    const int lh   = lane >> 4;
    const int rbase = blockIdx.x * 16;

    const float* Wih = layerS ? Wih1 : Wih0;
    const float* Whh = layerS ? Whh1 : Whh0;
    const float* bih = layerS ? bih1 : bih0;
    const float* bhh = layerS ? bhh1 : bhh0;

    // ---- weight frags -> regs (B-frag: col=l15, k = lh*8+j within my k-half) ----
    f16x8 wh[4];     // Whh, my k-half, q=0..3
    f16x8 xw[4];     // layer1: Wih my k-half q=0..3; layer0: full-K=32, zero unless (q>>1)==roleS
    float biasv[4];
#pragma unroll
    for (int q = 0; q < 4; ++q) {
        const int g = (hctS + 4 * q) * 16 + l15;   // gate col; q=0:i 1:f 2:g 3:o
        {
            const float* p = Whh + g * H_ + roleS * 32 + lh * 8;
            f16x8 v;
#pragma unroll
            for (int j = 0; j < 8; ++j) v[j] = (f16)p[j];
            wh[q] = v;
        }
        if (layerS) {
            const float* p = Wih + g * H_ + roleS * 32 + lh * 8;
            f16x8 v;
#pragma unroll
            for (int j = 0; j < 8; ++j) v[j] = (f16)p[j];
            xw[q] = v;
        } else {
            // zero-weight trick: only my two q's carry real Wih
            const bool own = ((q >> 1) == roleS);
            const float* p = Wih + g * DD_;
            f16x8 v;
#pragma unroll
            for (int j = 0; j < 8; ++j) {
                const int k = lh * 8 + j;
                v[j] = (own && k < DD_) ? (f16)p[k] : (f16)0.0f;
            }
            xw[q] = v;
        }
        biasv[q] = bih[g] + bhh[g];
    }

    // out-projection (dec): waves wv==5 (d 0-15), wv==7 (d 16-20), full-K
    f16x8 bO[2];
    float obias = 0.0f;
    const bool projw = IS_DEC && (layerS == 0) && roleS == 1 && hctS >= 2;   // scalar
    if (IS_DEC) {
        const int dt = hctS - 2;
        const bool pvalid = projw && (dt * 16 + l15 < DD_);
        const int d = pvalid ? (dt * 16 + l15) : 0;
#pragma unroll
        for (int kt = 0; kt < 2; ++kt) {
            f16x8 v;
#pragma unroll
            for (int j = 0; j < 8; ++j)
                v[j] = pvalid ? (f16)outW[d * H_ + kt * 32 + lh * 8 + j] : (f16)0.0f;
            bO[kt] = v;
        }
        if (pvalid) obias = outb[d];
    }

    // ---- init ring slot 1 with h(-1): h0p (dec) or zeros (enc) ----
    if (tid < 512) {
        f16* ring = (tid < 256) ? ring0 : ring1;
        const int i = tid & 255;
        const int row = i >> 4;
        const int cq = i & 15;
        f16x4 v;
#pragma unroll
        for (int j = 0; j < 4; ++j)
            v[j] = IS_DEC ? (f16)h0p[(size_t)(rbase + row) * H_ + cq * 4 + j] : (f16)0.0f;
        char* base = (char*)(ring + 1024);
        *(f16x4*)(base + row * 128 + ((cq * 8) ^ ((row & 7) << 4))) = v;
    }

    float c2[2] = {0.f, 0.f};

    // ---- layer0 x prefetch (distance 2) ----
    auto xaddr = [&](int t) -> const f16* {
        const int trd = IS_DEC ? (T_ - 1 - t) : t;
        return xpad + ((size_t)(rbase + l15) * T_ + trd) * DP_ + lh * 8;
    };
    f16x8 xA, pf[2];
    if (layerS == 0) {
        xA = *(const f16x8*)xaddr(0);
        pf[1] = *(const f16x8*)xaddr(1);
    }

    __syncthreads();   // ring init visible

    const f32x4 zero4 = {0.f, 0.f, 0.f, 0.f};

#pragma unroll 2
    for (int s = 0; s < 130; ++s) {
        const bool act0 = (layerS == 0) ? (s < T_) : (s >= 1 && s <= T_);   // scalar
        f32x4 acc[4];

        // ================= phase 1: partial MFMAs + exchange write =================
        if (layerS == 0) {
            if (act0) {
                const int tf = (s + 2 < T_) ? s + 2 : T_ - 1;
                pf[s & 1] = *(const f16x8*)xaddr(tf);
                const f16x8 hA = ring_read_frag(ring0, (s + 1) & 1, l15, lh, roleS);
#pragma unroll
                for (int q = 0; q < 4; ++q) acc[q] = MFMA16(hA, wh[q], zero4);
                // branchless x-contribution: partner-owned q's have zero weights
#pragma unroll
                for (int q = 0; q < 4; ++q) acc[q] = MFMA16(xA, xw[q], acc[q]);
            }
            // deferred output projection of h2(s-2), full-K, no exchange
            if (projw && s >= 2) {
                f16x8 pA0, pA1;
                ring_read_full(ring1, s & 1, l15, lh, pA0, pA1);
                f32x4 ao = {obias, obias, obias, obias};
                ao = MFMA16(pA0, bO[0], ao);
                ao = MFMA16(pA1, bO[1], ao);
                const int d = (hctS - 2) * 16 + l15;
                if (d < DD_) {
                    const int t = s - 2;
#pragma unroll
                    for (int r = 0; r < 4; ++r)
                        rec_out[((size_t)(rbase + lh * 4 + r) * T_ + (T_ - 1 - t)) * DD_ + d] = ao[r];
                }
            }
        } else {
            if (act0) {
                const f16x8 h1A = ring_read_frag(ring0, (s + 1) & 1, l15, lh, roleS);
                const f16x8 h2A = ring_read_frag(ring1, s & 1, l15, lh, roleS);
#pragma unroll
                for (int q = 0; q < 4; ++q) {
                    f32x4 a = MFMA16(h1A, xw[q], zero4);
                    acc[q] = MFMA16(h2A, wh[q], a);
                }
            }
        }
        if (act0) {
            // send the two rows my partner owns (constant component indices)
#pragma unroll
            for (int q = 0; q < 4; ++q) {
                const float s0 = roleS ? acc[q][0] : acc[q][2];
                const float s1 = roleS ? acc[q][1] : acc[q][3];
                exch[pidxS][roleS ^ 1][q][lane] = (f32x2){s0, s1};
            }
        }
        __syncthreads();   // B1: exchange visible

        // ================= phase 2: sum partials, activations, ring write =========
        if (act0) {
            f32x2 g[4];
#pragma unroll
            for (int q = 0; q < 4; ++q) g[q] = exch[pidxS][roleS][q][lane];
            f16 hh[2];
            float hvf[2];
#pragma unroll
            for (int rloc = 0; rloc < 2; ++rloc) {
                const float mi = roleS ? acc[0][2 + rloc] : acc[0][rloc];
                const float mf = roleS ? acc[1][2 + rloc] : acc[1][rloc];
                const float mg = roleS ? acc[2][2 + rloc] : acc[2][rloc];
                const float mo = roleS ? acc[3][2 + rloc] : acc[3][rloc];
                const float iv = sigmoid_(mi + g[0][rloc] + biasv[0]);
                const float fv = sigmoid_(mf + g[1][rloc] + biasv[1]);
                const float gv = tanh_(mg + g[2][rloc] + biasv[2]);
                const float ov = sigmoid_(mo + g[3][rloc] + biasv[3]);
                const float cn = fv * c2[rloc] + iv * gv;
                c2[rloc] = cn;
                hvf[rloc] = ov * tanh_(cn);
                hh[rloc] = (f16)hvf[rloc];
            }
            // ring write: my 2 rows (row = lh*4 + rkS + rloc)
            f16* ring = layerS ? ring1 : ring0;
            const int slot = layerS ? ((s + 1) & 1) : (s & 1);
            char* base = (char*)(ring + slot * 1024);
            const int colb = (hctS * 16 + l15) * 2;
#pragma unroll
            for (int rloc = 0; rloc < 2; ++rloc) {
                const int row = lh * 4 + rkS + rloc;
                *(f16*)(base + row * 128 + (colb ^ ((row & 7) << 4))) = hh[rloc];
            }
            if (!IS_DEC && layerS && s == T_) {
#pragma unroll
                for (int rloc = 0; rloc < 2; ++rloc)
                    hT_out[(size_t)(rbase + lh * 4 + rkS + rloc) * H_ + hctS * 16 + l15] = hvf[rloc];
            }
            if (layerS == 0) xA = pf[(s + 1) & 1];
        }
        __syncthreads();   // B2: ring visible
    }
}

// latent = hT2 @ tlW^T + tlb ; h0 = latent @ flW^T + flb   (tiny, fp32 VALU)
__global__ __launch_bounds__(256)
void latent_k(const float* __restrict__ hT, const float* __restrict__ tlW,
              const float* __restrict__ tlb, const float* __restrict__ flW,
              const float* __restrict__ flb, float* __restrict__ lat_out,
              float* __restrict__ h0_out)
{
    __shared__ float lat[64][L_];
    const int tid = threadIdx.x;
    const int r = tid >> 2;
    const int rb = blockIdx.x * 64;

    float hr[H_];
    const float* hrow = hT + (size_t)(rb + r) * H_;
#pragma unroll
    for (int k = 0; k < H_; ++k) hr[k] = hrow[k];

    const int c8 = (tid & 3) * 8;
#pragma unroll
    for (int jj = 0; jj < 8; ++jj) {
        const int l = c8 + jj;
        float s = tlb[l];
        const float* wrow = tlW + l * H_;
#pragma unroll
        for (int k = 0; k < H_; ++k) s += hr[k] * wrow[k];
        lat[r][l] = s;
        lat_out[(size_t)(rb + r) * L_ + l] = s;
    }
    __syncthreads();

    float lr[L_];
#pragma unroll
    for (int k = 0; k < L_; ++k) lr[k] = lat[r][k];
    const int hc16 = (tid & 3) * 16;
#pragma unroll
    for (int jj = 0; jj < 16; ++jj) {
        const int hc = hc16 + jj;
        float s = flb[hc];
        const float* wrow = flW + hc * L_;
#pragma unroll
        for (int k = 0; k < L_; ++k) s += lr[k] * wrow[k];
        h0_out[(size_t)(rb + r) * H_ + hc] = s;
    }
}

extern "C" void kernel_launch(void* const* d_in, const int* in_sizes, int n_in,
                              void* d_out, int out_size, void* d_ws, size_t ws_size,
                              hipStream_t stream)
{
    const float* x     = (const float*)d_in[0];
    const float* eWih0 = (const float*)d_in[1];
    const float* eWhh0 = (const float*)d_in[2];
    const float* ebih0 = (const float*)d_in[3];
    const float* ebhh0 = (const float*)d_in[4];
    const float* eWih1 = (const float*)d_in[5];
    const float* eWhh1 = (const float*)d_in[6];
    const float* ebih1 = (const float*)d_in[7];
    const float* ebhh1 = (const float*)d_in[8];
    const float* dWih0 = (const float*)d_in[9];
    const float* dWhh0 = (const float*)d_in[10];
    const float* dbih0 = (const float*)d_in[11];
    const float* dbhh0 = (const float*)d_in[12];
    const float* dWih1 = (const float*)d_in[13];
    const float* dWhh1 = (const float*)d_in[14];
    const float* dbih1 = (const float*)d_in[15];
    const float* dbhh1 = (const float*)d_in[16];
    const float* tlW   = (const float*)d_in[17];
    const float* tlb   = (const float*)d_in[18];
    const float* flW   = (const float*)d_in[19];
    const float* flb   = (const float*)d_in[20];
    const float* outW  = (const float*)d_in[21];
    const float* outb  = (const float*)d_in[22];

    float* rec = (float*)d_out;                       // [B,T,21] fp32
    float* lat = rec + (size_t)B_ * T_ * DD_;         // [B,32]  fp32

    char* ws = (char*)d_ws;
    f16*   xpad = (f16*)ws;                                            // [B,T,32] f16
    float* hT2  = (float*)(ws + (size_t)B_ * T_ * DP_ * 2);            // [B,64]
    float* h0   = (float*)(ws + (size_t)B_ * T_ * DP_ * 2 + (size_t)B_ * H_ * 4); // [B,64]

    // pad/cast x once per call
    padx_k<<<dim3(B_ * T_ * 8 / 256), dim3(256), 0, stream>>>(x, xpad);
    // fused encoder pair -> hT2
    lstm_pair_k<false><<<dim3(B_ / 16), dim3(1024), 0, stream>>>(
        xpad, eWih0, eWhh0, ebih0, ebhh0, eWih1, eWhh1, ebih1, ebhh1,
        nullptr, hT2, nullptr, nullptr, nullptr);
    // latent + decoder initial h
    latent_k<<<dim3(B_ / 64), dim3(256), 0, stream>>>(hT2, tlW, tlb, flW, flb, lat, h0);
    // fused decoder pair -> rec (fused out-proj, time-reversed store)
    lstm_pair_k<true><<<dim3(B_ / 16), dim3(1024), 0, stream>>>(
        xpad, dWih0, dWhh0, dbih0, dbhh0, dWih1, dWhh1, dbih1, dbhh1,
        h0, nullptr, outW, outb, rec);
}

// Round 8
// 382.296 us; speedup vs baseline: 2.4781x; 1.5541x over previous
//
#include <hip/hip_runtime.h>

#define B_ 4096
#define T_ 128
#define DD_ 21
#define H_ 64
#define L_ 32
#define DP_ 32   // layer-0 input dim padded to 32 (f16)

typedef _Float16 f16;
typedef _Float16 f16x8 __attribute__((ext_vector_type(8)));
typedef _Float16 f16x4 __attribute__((ext_vector_type(4)));
typedef float f32x4 __attribute__((ext_vector_type(4)));

#if __has_builtin(__builtin_amdgcn_exp2f)
#define EXP2F(x) __builtin_amdgcn_exp2f(x)
#else
#define EXP2F(x) exp2f(x)
#endif
#if __has_builtin(__builtin_amdgcn_rcpf)
#define RCPF(x) __builtin_amdgcn_rcpf(x)
#else
#define RCPF(x) (1.0f / (x))
#endif

// Prescaled activation forms: weight rows for i,f,o carry factor -1.4426950,
// g rows carry +2.8853901, so no argument multiply is needed here.
__device__ __forceinline__ float sigmoid_pre(float y) {   // y = -1.4427*x
    return RCPF(1.0f + EXP2F(y));
}
__device__ __forceinline__ float tanh_pre(float y) {      // y = +2.8854*x
    return 1.0f - 2.0f * RCPF(1.0f + EXP2F(y));
}
__device__ __forceinline__ float tanh_(float x) {         // unscaled (for tanh(c))
    return 1.0f - 2.0f * RCPF(1.0f + EXP2F(2.8853900817779268f * x));
}

#define MFMA16(A, Bf, C) __builtin_amdgcn_mfma_f32_16x16x32_f16((A), (Bf), (C), 0, 0, 0)

// ---- h rings: [2 slots][16 rows][64 cols] f16, XOR-swizzled rows ----
__device__ __forceinline__ void ring_read(const f16* ring, int slot, int l15, int lh,
                                          f16x8& a0, f16x8& a1) {
    const char* base = (const char*)(ring + slot * 1024);
    const int sw = (l15 & 7) << 4;
    a0 = *(const f16x8*)(base + l15 * 128 + ((lh * 16) ^ sw));
    a1 = *(const f16x8*)(base + l15 * 128 + ((64 + lh * 16) ^ sw));
}
__device__ __forceinline__ void ring_write(f16* ring, int slot, int w, int l15, int lh,
                                           const f16* hh) {
    char* base = (char*)(ring + slot * 1024);
    const int colb = (w * 16 + l15) * 2;
#pragma unroll
    for (int r = 0; r < 4; ++r) {
        const int row = lh * 4 + r;
        *(f16*)(base + row * 128 + (colb ^ ((row & 7) << 4))) = hh[r];
    }
}

// x pad/cast: x f32 [B,T,21] -> xpad f16 [B,T,32] (zero-padded)
__global__ __launch_bounds__(256)
void padx_k(const float* __restrict__ x, f16* __restrict__ xpad)
{
    const int idx = blockIdx.x * blockDim.x + threadIdx.x;   // B*T*8 groups of 4
    const size_t bt = (size_t)(idx >> 3);
    const int k0 = (idx & 7) * 4;
    const float* src = x + bt * DD_;
    f16x4 v;
#pragma unroll
    for (int j = 0; j < 4; ++j) {
        const int k = k0 + j;
        v[j] = (k < DD_) ? (f16)src[k] : (f16)0.0f;
    }
    *(f16x4*)(xpad + bt * DP_ + k0) = v;
}

// Fused layer pair with 1-step pipeline skew, weights in registers (round-4
// skeleton: 512 thr = 8 waves; waves 0-3 layer0 @ t=s, waves 4-7 layer1 @ t=s-1).
// Round-8 changes (mechanism-targeted):
//  * x loads batched 4 steps per issue (double-buffered regs) -> 3 of 4 barriers
//    have nothing outstanding in vmcnt; 4-step latency cover; less addr VALU.
//  * weights prescaled by the activation argument constants (i,f,o: -1.4427;
//    g: +2.8854) -> no per-gate argument multiply, shorter act dep chain.
//  * decoder proj stores batched 4 steps per flush (regs) -> store-ack drains
//    off the per-step barrier path.
template<bool IS_DEC>
__global__
__attribute__((amdgpu_flat_work_group_size(512, 512), amdgpu_waves_per_eu(2, 2)))
void lstm_pair_k(const f16* __restrict__ xpad,
                 const float* __restrict__ Wih0, const float* __restrict__ Whh0,
                 const float* __restrict__ bih0, const float* __restrict__ bhh0,
                 const float* __restrict__ Wih1, const float* __restrict__ Whh1,
                 const float* __restrict__ bih1, const float* __restrict__ bhh1,
                 const float* __restrict__ h0p,
                 float* __restrict__ hT_out,
                 const float* __restrict__ outW, const float* __restrict__ outb,
                 float* __restrict__ rec_out)
{
    __shared__ __align__(16) f16 ring0[2 * 1024];   // h1 ring (4 KB)
    __shared__ __align__(16) f16 ring1[2 * 1024];   // h2 ring (4 KB)

    const int tid  = threadIdx.x;
    const int wv   = tid >> 6;
    const int grp  = wv >> 2;         // 0: layer0, 1: layer1
    const int w    = wv & 3;
    const int lane = tid & 63;
    const int l15  = lane & 15;
    const int lh   = lane >> 4;
    const int rbase = blockIdx.x * 16;

    const float* Wih = grp ? Wih1 : Wih0;
    const float* Whh = grp ? Whh1 : Whh0;
    const float* bih = grp ? bih1 : bih0;
    const float* bhh = grp ? bhh1 : bhh0;

    // ---- weight fragments -> VGPRs, PRESCALED (B-frag: col=l15, k=lh*8+j) ----
    f16x8 wR[8];    // Whh frags [q*2+kt]
    f16x8 xR[8];    // Wih frags: grp1 [q*2+kt]; grp0 [q] (K=32)
    f32x4 bias4[4];
#pragma unroll
    for (int q = 0; q < 4; ++q) {
        const float gs = (q == 2) ? 2.8853900817779268f : -1.4426950408889634f;
        const int g = (w + 4 * q) * 16 + l15;   // gate row in W; q=0:i 1:f 2:g 3:o
#pragma unroll
        for (int kt = 0; kt < 2; ++kt) {
            const float* p = Whh + g * H_ + kt * 32 + lh * 8;
            f16x8 v;
#pragma unroll
            for (int j = 0; j < 8; ++j) v[j] = (f16)(gs * p[j]);
            wR[q * 2 + kt] = v;
        }
        if (grp) {
#pragma unroll
            for (int kt = 0; kt < 2; ++kt) {
                const float* p = Wih + g * H_ + kt * 32 + lh * 8;
                f16x8 v;
#pragma unroll
                for (int j = 0; j < 8; ++j) v[j] = (f16)(gs * p[j]);
                xR[q * 2 + kt] = v;
            }
        } else {
            const float* p = Wih + g * DD_;     // real row length 21
            f16x8 v;
#pragma unroll
            for (int j = 0; j < 8; ++j) {
                const int k = lh * 8 + j;
                v[j] = (k < DD_) ? (f16)(gs * p[k]) : (f16)0.0f;
            }
            xR[q] = v;
        }
        const float bv = gs * (bih[g] + bhh[g]);
        bias4[q] = (f32x4){bv, bv, bv, bv};
    }

    // out-projection frags: dec only, grp0 waves 2-3 (d = (w-2)*16 + l15) — NOT scaled
    f16x8 bO[2];
    float obias = 0.0f;
    if (IS_DEC && grp == 0) {
        const bool pvalid = (w >= 2) && ((w - 2) * 16 + l15 < DD_);
        const int d = pvalid ? ((w - 2) * 16 + l15) : 0;
#pragma unroll
        for (int kt = 0; kt < 2; ++kt) {
            f16x8 v;
#pragma unroll
            for (int j = 0; j < 8; ++j)
                v[j] = pvalid ? (f16)outW[d * H_ + kt * 32 + lh * 8 + j] : (f16)0.0f;
            bO[kt] = v;
        }
        if (pvalid) obias = outb[d];
    }

    // ---- init ring slot 1 with h(-1): h0p (dec) or zeros (enc) ----
    {
        f16* ring = (tid < 256) ? ring0 : ring1;
        const int i = tid & 255;
        const int row = i >> 4;
        const int cq = i & 15;
        f16x4 v;
#pragma unroll
        for (int j = 0; j < 4; ++j)
            v[j] = IS_DEC ? (f16)h0p[(size_t)(rbase + row) * H_ + cq * 4 + j] : (f16)0.0f;
        char* base = (char*)(ring + 1024);
        *(f16x4*)(base + row * 128 + ((cq * 8) ^ ((row & 7) << 4))) = v;
    }

    f32x4 c4 = {0.f, 0.f, 0.f, 0.f};

    // ---- x batch buffers: 4 steps per issue, double-buffered ----
    auto ldx = [&](int t) -> f16x8 {
        const int tc  = (t < T_) ? t : (T_ - 1);
        const int trd = IS_DEC ? (T_ - 1 - tc) : tc;
        return *(const f16x8*)(xpad + ((size_t)(rbase + l15) * T_ + trd) * DP_ + lh * 8);
    };
    f16x8 xbA[4], xbB[4];
    if (grp == 0) {
#pragma unroll
        for (int j = 0; j < 4; ++j) xbA[j] = ldx(j);   // steps 0..3
    }

    f32x4 pbuf[4];   // dec proj batch (grp0 w>=2 only; dead elsewhere)

    __syncthreads();   // ring init visible

    // ---- pipelined main loop: 17 periods x 8 steps (s = 0..135; 130 live) ----
    for (int so = 0; so < 17; ++so) {
#pragma unroll
        for (int k = 0; k < 8; ++k) {
            const int s = so * 8 + k;
            if (grp == 0) {
                // batch-issue x loads: k==0 covers steps so*8+4..7 (xbB),
                // k==4 covers steps so*8+8..11 (xbA). 4-step latency cover.
                if (k == 0) {
#pragma unroll
                    for (int j = 0; j < 4; ++j) xbB[j] = ldx(so * 8 + 4 + j);
                }
                if (k == 4) {
#pragma unroll
                    for (int j = 0; j < 4; ++j) xbA[j] = ldx(so * 8 + 8 + j);
                }
                if (s < T_) {
                    const f16x8 xk = (k < 4) ? xbA[k] : xbB[k - 4];   // k literal -> folds
                    f16x8 hA0, hA1;
                    ring_read(ring0, (s + 1) & 1, l15, lh, hA0, hA1);
                    f32x4 acc[4];
#pragma unroll
                    for (int q = 0; q < 4; ++q) {
                        f32x4 a = MFMA16(xk, xR[q], bias4[q]);
                        a = MFMA16(hA0, wR[q * 2 + 0], a);
                        a = MFMA16(hA1, wR[q * 2 + 1], a);
                        acc[q] = a;
                    }
                    f16 hh[4];
#pragma unroll
                    for (int r = 0; r < 4; ++r) {
                        const float iv = sigmoid_pre(acc[0][r]);
                        const float fv = sigmoid_pre(acc[1][r]);
                        const float gv = tanh_pre(acc[2][r]);
                        const float ov = sigmoid_pre(acc[3][r]);
                        const float cn = fv * c4[r] + iv * gv;
                        c4[r] = cn;
                        hh[r] = (f16)(ov * tanh_(cn));
                    }
                    ring_write(ring0, s & 1, w, l15, lh, hh);
                }
                // deferred output projection of h2(s-2) on waves 2-3 (dec only)
                if (IS_DEC && w >= 2) {
                    if (s >= 2 && s <= T_ + 1) {
                        f16x8 pA0, pA1;
                        ring_read(ring1, s & 1, l15, lh, pA0, pA1);
                        f32x4 ao = {obias, obias, obias, obias};
                        ao = MFMA16(pA0, bO[0], ao);
                        ao = MFMA16(pA1, bO[1], ao);
                        pbuf[k & 3] = ao;        // k literal -> static slot
                    }
                    if (k == 3 || k == 7) {      // flush 4 steps of proj output
                        const int sb = so * 8 + (k & 4);
                        const int d = (w - 2) * 16 + l15;
                        if (d < DD_) {
#pragma unroll
                            for (int j = 0; j < 4; ++j) {
                                const int sj = sb + j;
                                if (sj >= 2 && sj <= T_ + 1) {
                                    const int t = sj - 2;
#pragma unroll
                                    for (int r = 0; r < 4; ++r)
                                        rec_out[((size_t)(rbase + lh * 4 + r) * T_ + (T_ - 1 - t)) * DD_ + d] = pbuf[j][r];
                                }
                            }
                        }
                    }
                }
            } else {
                if (s >= 1 && s <= T_) {
                    // own recurrence h2(s-2) from ring1 slot s&1
                    f16x8 hA0, hA1;
                    ring_read(ring1, s & 1, l15, lh, hA0, hA1);
                    // h1(s-1) from ring0 slot (s+1)&1
                    f16x8 xA0, xA1;
                    ring_read(ring0, (s + 1) & 1, l15, lh, xA0, xA1);
                    f32x4 acc[4];
#pragma unroll
                    for (int q = 0; q < 4; ++q) {
                        f32x4 a = MFMA16(xA0, xR[q * 2 + 0], bias4[q]);
                        a = MFMA16(xA1, xR[q * 2 + 1], a);
                        a = MFMA16(hA0, wR[q * 2 + 0], a);
                        a = MFMA16(hA1, wR[q * 2 + 1], a);
                        acc[q] = a;
                    }
                    f16 hh[4];
                    float hvf[4];
#pragma unroll
                    for (int r = 0; r < 4; ++r) {
                        const float iv = sigmoid_pre(acc[0][r]);
                        const float fv = sigmoid_pre(acc[1][r]);
                        const float gv = tanh_pre(acc[2][r]);
                        const float ov = sigmoid_pre(acc[3][r]);
                        const float cn = fv * c4[r] + iv * gv;
                        c4[r] = cn;
                        hvf[r] = ov * tanh_(cn);
                        hh[r] = (f16)hvf[r];
                    }
                    ring_write(ring1, (s + 1) & 1, w, l15, lh, hh);
                    if (!IS_DEC && s == T_) {
#pragma unroll
                        for (int r = 0; r < 4; ++r)
                            hT_out[(size_t)(rbase + lh * 4 + r) * H_ + w * 16 + l15] = hvf[r];
                    }
                }
            }
            __syncthreads();
        }
    }
}

// latent = hT2 @ tlW^T + tlb ; h0 = latent @ flW^T + flb   (tiny, fp32 VALU)
__global__ __launch_bounds__(256)
void latent_k(const float* __restrict__ hT, const float* __restrict__ tlW,
              const float* __restrict__ tlb, const float* __restrict__ flW,
              const float* __restrict__ flb, float* __restrict__ lat_out,
              float* __restrict__ h0_out)
{
    __shared__ float lat[64][L_];
    const int tid = threadIdx.x;
    const int r = tid >> 2;
    const int rb = blockIdx.x * 64;

    float hr[H_];
    const float* hrow = hT + (size_t)(rb + r) * H_;
#pragma unroll
    for (int k = 0; k < H_; ++k) hr[k] = hrow[k];

    const int c8 = (tid & 3) * 8;
#pragma unroll
    for (int jj = 0; jj < 8; ++jj) {
        const int l = c8 + jj;
        float s = tlb[l];
        const float* wrow = tlW + l * H_;
#pragma unroll
        for (int k = 0; k < H_; ++k) s += hr[k] * wrow[k];
        lat[r][l] = s;
        lat_out[(size_t)(rb + r) * L_ + l] = s;
    }
    __syncthreads();

    float lr[L_];
#pragma unroll
    for (int k = 0; k < L_; ++k) lr[k] = lat[r][k];
    const int hc16 = (tid & 3) * 16;
#pragma unroll
    for (int jj = 0; jj < 16; ++jj) {
        const int hc = hc16 + jj;
        float s = flb[hc];
        const float* wrow = flW + hc * L_;
#pragma unroll
        for (int k = 0; k < L_; ++k) s += lr[k] * wrow[k];
        h0_out[(size_t)(rb + r) * H_ + hc] = s;
    }
}

extern "C" void kernel_launch(void* const* d_in, const int* in_sizes, int n_in,
                              void* d_out, int out_size, void* d_ws, size_t ws_size,
                              hipStream_t stream)
{
    const float* x     = (const float*)d_in[0];
    const float* eWih0 = (const float*)d_in[1];
    const float* eWhh0 = (const float*)d_in[2];
    const float* ebih0 = (const float*)d_in[3];
    const float* ebhh0 = (const float*)d_in[4];
    const float* eWih1 = (const float*)d_in[5];
    const float* eWhh1 = (const float*)d_in[6];
    const float* ebih1 = (const float*)d_in[7];
    const float* ebhh1 = (const float*)d_in[8];
    const float* dWih0 = (const float*)d_in[9];
    const float* dWhh0 = (const float*)d_in[10];
    const float* dbih0 = (const float*)d_in[11];
    const float* dbhh0 = (const float*)d_in[12];
    const float* dWih1 = (const float*)d_in[13];
    const float* dWhh1 = (const float*)d_in[14];
    const float* dbih1 = (const float*)d_in[15];
    const float* dbhh1 = (const float*)d_in[16];
    const float* tlW   = (const float*)d_in[17];
    const float* tlb   = (const float*)d_in[18];
    const float* flW   = (const float*)d_in[19];
    const float* flb   = (const float*)d_in[20];
    const float* outW  = (const float*)d_in[21];
    const float* outb  = (const float*)d_in[22];

    float* rec = (float*)d_out;                       // [B,T,21] fp32
    float* lat = rec + (size_t)B_ * T_ * DD_;         // [B,32]  fp32

    char* ws = (char*)d_ws;
    f16*   xpad = (f16*)ws;                                            // [B,T,32] f16
    float* hT2  = (float*)(ws + (size_t)B_ * T_ * DP_ * 2);            // [B,64]
    float* h0   = (float*)(ws + (size_t)B_ * T_ * DP_ * 2 + (size_t)B_ * H_ * 4); // [B,64]

    // pad/cast x once per call
    padx_k<<<dim3(B_ * T_ * 8 / 256), dim3(256), 0, stream>>>(x, xpad);
    // fused encoder pair -> hT2
    lstm_pair_k<false><<<dim3(B_ / 16), dim3(512), 0, stream>>>(
        xpad, eWih0, eWhh0, ebih0, ebhh0, eWih1, eWhh1, ebih1, ebhh1,
        nullptr, hT2, nullptr, nullptr, nullptr);
    // latent + decoder initial h
    latent_k<<<dim3(B_ / 64), dim3(256), 0, stream>>>(hT2, tlW, tlb, flW, flb, lat, h0);
    // fused decoder pair -> rec (fused out-proj on grp0 w2-3, time-reversed store)
    lstm_pair_k<true><<<dim3(B_ / 16), dim3(512), 0, stream>>>(
        xpad, dWih0, dWhh0, dbih0, dbhh0, dWih1, dWhh1, dbih1, dbhh1,
        h0, nullptr, outW, outb, rec);
}